// Round 5
// baseline (448.358 us; speedup 1.0000x reference)
//
#include <hip/hip_runtime.h>
#include <hip/hip_bf16.h>

// ClassAtt fused pipeline. GEMMs: 256x256-tile, BK=32, 4-slot ring staging
// (counted vmcnt), LDS XOR-swizzle, XCD swizzle.
// R5: 8-phase-style compute schedule (m201 template): each BK=32 tile = 2
// phases of 16 MFMAs, each phase {ds_reads; [stage]; bar; lgkm(0);
// sched_barrier; setprio1; 16 MFMA; setprio0; bar}. Counted vmcnt once per
// tile, never 0 in steady state. Ring invariants identical to R2 (verified).

typedef __bf16 bf16_t;
typedef __bf16 bf16x4 __attribute__((ext_vector_type(4)));
typedef __bf16 bf16x8 __attribute__((ext_vector_type(8)));
typedef float  f32x4  __attribute__((ext_vector_type(4)));

#define AS1(p) (const __attribute__((address_space(1))) void*)(p)
#define AS3(p) (__attribute__((address_space(3))) void*)(p)

// ---------------- f32 -> bf16 conversion (vectorized, zero-pad tail) ----------------
__global__ void cvt_f32_bf16_v4(const float* __restrict__ src, bf16_t* __restrict__ dst,
                                int n4src, int n4tot) {
  for (int i = blockIdx.x * blockDim.x + threadIdx.x; i < n4tot; i += gridDim.x * blockDim.x) {
    bf16x4 o;
    if (i < n4src) {
      float4 f = ((const float4*)src)[i];
      o[0] = (bf16_t)f.x; o[1] = (bf16_t)f.y; o[2] = (bf16_t)f.z; o[3] = (bf16_t)f.w;
    } else {
      o[0] = (bf16_t)0.0f; o[1] = (bf16_t)0.0f; o[2] = (bf16_t)0.0f; o[3] = (bf16_t)0.0f;
    }
    *(bf16x4*)(dst + (size_t)i * 4) = o;
  }
}

__global__ void concat_bias3(const float* __restrict__ a, const float* __restrict__ b,
                             const float* __restrict__ c, float* __restrict__ dst) {
  int i = blockIdx.x * blockDim.x + threadIdx.x;
  if (i < 1024) dst[i] = a[i];
  else if (i < 2048) dst[i] = b[i - 1024];
  else if (i < 3072) dst[i] = c[i - 2048];
}

// ---------------- GEMM: C = act(A @ Bw^T + bias), 256x256 tile ----------------
// 512 threads = 8 waves (2 M x 4 N), each wave owns a 128x64 output sub-tile
// (acc[8][4] of 16x16 frags). LDS: 4-slot ring of (A 256x32 + B 256x32) bf16
// = 128 KiB dynamic. Stage tile j+3 during tile j; steady wait vmcnt(8).
template<bool BDIAG, bool RELU, bool OUT_BF16>
__global__ __launch_bounds__(512, 2)
void gemm256(const bf16_t* __restrict__ A, int lda,
             const bf16_t* __restrict__ Bw, int ldb,
             const float* __restrict__ bias,
             void* __restrict__ Cout, int ldc,
             int K, int Nmask, int nbx)
{
  extern __shared__ char lds[];
  bf16_t* Ab = (bf16_t*)lds;               // 4 slots x 8192 elems (16 KiB/slot)
  bf16_t* Bb = (bf16_t*)(lds + 65536);

  const int t   = threadIdx.x;
  const int ln  = t & 63;
  const int w   = t >> 6;
  const int l15 = ln & 15, lhi = ln >> 4;
  const int wm  = w >> 2, wn = w & 3;

  // XCD-chunked block swizzle (grid divisible by 8)
  const int nb = (int)gridDim.x;
  const int id = (int)blockIdx.x;
  const int id_sw = (id & 7) * (nb >> 3) + (id >> 3);
  const int bx = id_sw % nbx, by = id_sw / nbx;
  const int rowBase = by * 256;
  const int colBase = bx * 256;
  const int aCol0 = BDIAG ? (colBase >> 10) * 512 : 0;

  // staging: wave w, lane ln -> LDS linear byte i*8192 + w*1024 + ln*16
  //   (row = i*128 + w*16 + ln/4); source col pre-swizzled involution.
  const int srow = (w << 4) + (ln >> 2);
  const int scol = (((ln & 3) ^ (ln >> 3)) & 3) << 3;

  const bf16_t* aS = A  + (size_t)(rowBase + srow) * lda + aCol0 + scol;
  const bf16_t* bS = Bw + (size_t)(colBase + srow) * ldb + scol;
  const size_t aI = (size_t)128 * lda;
  const size_t bI = (size_t)128 * ldb;
  bf16_t* daW = Ab + (w << 9);
  bf16_t* dbW = Bb + (w << 9);

  // fragment read offsets (elements), same swizzle involution
  const int key  = (l15 >> 1) & 3;
  const int fcol = (lhi ^ key) << 3;
  const int aOff = (wm * 128 + l15) * 32 + fcol;   // + mf*512 + slot*8192
  const int bOff = (wn * 64  + l15) * 32 + fcol;   // + nf*512 + slot*8192

  const int nt = K >> 5;

  f32x4 acc[8][4] = {};
  bf16x8 af[8], bfr[4];

  #define STAGE(kt, s)                                                              \
    do {                                                                            \
      const bf16_t* a_ = aS + (size_t)(kt) * 32;                                    \
      const bf16_t* b_ = bS + (size_t)(kt) * 32;                                    \
      bf16_t* da_ = daW + (s) * 8192;                                               \
      bf16_t* db_ = dbW + (s) * 8192;                                               \
      __builtin_amdgcn_global_load_lds(AS1(a_),      AS3(da_),        16, 0, 0);    \
      __builtin_amdgcn_global_load_lds(AS1(a_ + aI), AS3(da_ + 4096), 16, 0, 0);    \
      __builtin_amdgcn_global_load_lds(AS1(b_),      AS3(db_),        16, 0, 0);    \
      __builtin_amdgcn_global_load_lds(AS1(b_ + bI), AS3(db_ + 4096), 16, 0, 0);    \
    } while (0)

  // prologue: stage tiles 0..2; confirm tile 0 (8 = tiles 1,2 in flight)
  STAGE(0, 0); STAGE(1, 1); STAGE(2, 2);
  asm volatile("s_waitcnt vmcnt(8)" ::: "memory");
  __builtin_amdgcn_s_barrier();
  asm volatile("" ::: "memory");

  for (int j = 0; j < nt; ++j) {
    const int s = j & 3;
    const bf16_t* As_ = Ab + s * 8192 + aOff;
    const bf16_t* Bs_ = Bb + s * 8192 + bOff;

    // ======== phase 0: reads A0-3 + B0-3, stage j+3, MFMA mf0-3 x nf0-3 ========
    #pragma unroll
    for (int mf = 0; mf < 4; ++mf) af[mf] = *(const bf16x8*)(As_ + mf * 512);
    #pragma unroll
    for (int nf = 0; nf < 4; ++nf) bfr[nf] = *(const bf16x8*)(Bs_ + nf * 512);
    if (j + 3 < nt) STAGE(j + 3, ((j + 3) & 3));

    __builtin_amdgcn_s_barrier();
    asm volatile("s_waitcnt lgkmcnt(0)" ::: "memory");
    __builtin_amdgcn_sched_barrier(0);
    __builtin_amdgcn_s_setprio(1);
    #pragma unroll
    for (int mf = 0; mf < 4; ++mf)
      #pragma unroll
      for (int nf = 0; nf < 4; ++nf)
        acc[mf][nf] = __builtin_amdgcn_mfma_f32_16x16x32_bf16(af[mf], bfr[nf], acc[mf][nf], 0, 0, 0);
    __builtin_amdgcn_s_setprio(0);
    __builtin_amdgcn_s_barrier();
    asm volatile("" ::: "memory");

    // ======== phase 1: reads A4-7, counted vmcnt, MFMA mf4-7 x nf0-3 ========
    #pragma unroll
    for (int mf = 4; mf < 8; ++mf) af[mf] = *(const bf16x8*)(As_ + mf * 512);

    // counted vmcnt once per K-tile: confirm tile j+1 before the barrier after
    // which it will be read (phase 0 of iter j+1). Never 0 in steady state.
    if (j + 3 < nt) {
      asm volatile("s_waitcnt vmcnt(8)" ::: "memory");
    } else if (j + 2 < nt) {
      asm volatile("s_waitcnt vmcnt(4)" ::: "memory");
    } else if (j + 1 < nt) {
      asm volatile("s_waitcnt vmcnt(0)" ::: "memory");
    }

    __builtin_amdgcn_s_barrier();
    asm volatile("s_waitcnt lgkmcnt(0)" ::: "memory");
    __builtin_amdgcn_sched_barrier(0);
    __builtin_amdgcn_s_setprio(1);
    #pragma unroll
    for (int mf = 4; mf < 8; ++mf)
      #pragma unroll
      for (int nf = 0; nf < 4; ++nf)
        acc[mf][nf] = __builtin_amdgcn_mfma_f32_16x16x32_bf16(af[mf], bfr[nf], acc[mf][nf], 0, 0, 0);
    __builtin_amdgcn_s_setprio(0);
    __builtin_amdgcn_s_barrier();
    asm volatile("" ::: "memory");
  }
  #undef STAGE

  // epilogue: C/D layout col=l15, row=lhi*4+i (verified)
  #pragma unroll
  for (int mf = 0; mf < 8; ++mf) {
    const int row = rowBase + wm * 128 + mf * 16 + lhi * 4;
    #pragma unroll
    for (int nf = 0; nf < 4; ++nf) {
      const int col = colBase + wn * 64 + nf * 16 + l15;
      const float bv = (col < Nmask) ? bias[col] : 0.0f;
      #pragma unroll
      for (int i = 0; i < 4; ++i) {
        float v = acc[mf][nf][i] + bv;
        if (RELU) v = fmaxf(v, 0.0f);
        if (OUT_BF16) {
          ((bf16_t*)Cout)[(size_t)(row + i) * ldc + col] = (bf16_t)v;
        } else {
          if (col < Nmask) ((float*)Cout)[(size_t)(row + i) * ldc + col] = v;
        }
      }
    }
  }
}

// ---------------- alphas -> softmax -> context (one block per row) ----------------
__global__ __launch_bounds__(256)
void attn_ctx(const bf16_t* __restrict__ P, bf16_t* __restrict__ ds) {
  __shared__ float red[3][4];
  __shared__ float wsh[3];
  const int r = blockIdx.x;
  const int t = threadIdx.x;
  const bf16_t* Prow = P + (size_t)r * 3072;
  bf16_t* dsrow = ds + (size_t)r * 2048;

  const int j = t * 4;
  bf16x4 lv = *(const bf16x4*)(dsrow + 1024 + j);
  float lhv[4], pv[3][4];
  float s[3] = {0.f, 0.f, 0.f};
  #pragma unroll
  for (int q = 0; q < 4; q++) lhv[q] = (float)lv[q];
  #pragma unroll
  for (int e = 0; e < 3; e++) {
    bf16x4 p = *(const bf16x4*)(Prow + e * 1024 + j);
    #pragma unroll
    for (int q = 0; q < 4; q++) {
      pv[e][q] = (float)p[q];
      s[e] += lhv[q] * pv[e][q];
    }
  }
  #pragma unroll
  for (int off = 32; off > 0; off >>= 1) {
    #pragma unroll
    for (int e = 0; e < 3; e++) s[e] += __shfl_down(s[e], off, 64);
  }
  const int w = t >> 6, l = t & 63;
  if (l == 0) {
    #pragma unroll
    for (int e = 0; e < 3; e++) red[e][w] = s[e];
  }
  __syncthreads();
  if (t == 0) {
    float a0 = red[0][0] + red[0][1] + red[0][2] + red[0][3];
    float a1 = red[1][0] + red[1][1] + red[1][2] + red[1][3];
    float a2 = red[2][0] + red[2][1] + red[2][2] + red[2][3];
    float mx = fmaxf(a0, fmaxf(a1, a2));
    float e0 = expf(a0 - mx), e1 = expf(a1 - mx), e2 = expf(a2 - mx);
    float inv = 1.0f / (e0 + e1 + e2);
    wsh[0] = e0 * inv; wsh[1] = e1 * inv; wsh[2] = e2 * inv;
  }
  __syncthreads();
  const float w0 = wsh[0], w1 = wsh[1], w2 = wsh[2];
  bf16x4 o;
  #pragma unroll
  for (int q = 0; q < 4; q++)
    o[q] = (bf16_t)(w0 * pv[0][q] + w1 * pv[1][q] + w2 * pv[2][q]);
  *(bf16x4*)(dsrow + j) = o;
}

// ---------------- launch ----------------
extern "C" void kernel_launch(void* const* d_in, const int* in_sizes, int n_in,
                              void* d_out, int out_size, void* d_ws, size_t ws_size,
                              hipStream_t stream) {
  (void)in_sizes; (void)n_in; (void)out_size; (void)ws_size;

  const float* tube = (const float*)d_in[0];
  const float* w1W  = (const float*)d_in[1];
  const float* w1b  = (const float*)d_in[2];
  const float* w2W  = (const float*)d_in[3];
  const float* w2b  = (const float*)d_in[4];
  const float* w3W  = (const float*)d_in[5];
  const float* w3b  = (const float*)d_in[6];
  const float* whW  = (const float*)d_in[7];
  const float* whb  = (const float*)d_in[8];
  const float* wd1W = (const float*)d_in[9];
  const float* wd1b = (const float*)d_in[10];
  const float* wd2W = (const float*)d_in[11];
  const float* wd2b = (const float*)d_in[12];

  // workspace layout (bytes); out1 aliases {whB, w123B, tubeB} which are dead by G4.
  char* ws = (char*)d_ws;
  bf16_t* P       = (bf16_t*)(ws + 0);            // 16384x3072
  bf16_t* ds      = (bf16_t*)(ws + 100663296);    // 16384x2048
  bf16_t* wd1B    = (bf16_t*)(ws + 167772160);    // 2048x2048
  bf16_t* wd2B    = (bf16_t*)(ws + 176160768);    // 1024x2048 (rows 1000.. zero)
  bf16_t* whB     = (bf16_t*)(ws + 180355072);    // 1024x3072
  bf16_t* w123B   = (bf16_t*)(ws + 186646528);    // 3072x512
  bf16_t* tubeB   = (bf16_t*)(ws + 189792256);    // 16384x1536
  bf16_t* out1    = (bf16_t*)(ws + 180355072);    // 16384x2048, aliases whB..tubeB
  float*  bias123 = (float*)(ws + 247463936);     // 3072 f32

  // allow 128 KiB dynamic LDS for the gemm instantiations
  hipFuncSetAttribute((const void*)(gemm256<true,  true,  true >),
                      hipFuncAttributeMaxDynamicSharedMemorySize, 131072);
  hipFuncSetAttribute((const void*)(gemm256<false, true,  true >),
                      hipFuncAttributeMaxDynamicSharedMemorySize, 131072);
  hipFuncSetAttribute((const void*)(gemm256<false, false, false>),
                      hipFuncAttributeMaxDynamicSharedMemorySize, 131072);

  auto cvt = [&](const float* s, bf16_t* d, int n4s, int n4t) {
    int nb = (n4t + 255) / 256; if (nb > 2048) nb = 2048;
    hipLaunchKernelGGL(cvt_f32_bf16_v4, dim3(nb), dim3(256), 0, stream, s, d, n4s, n4t);
  };
  cvt(tube, tubeB, 6291456, 6291456);
  cvt(w1W,  w123B,           131072, 131072);
  cvt(w2W,  w123B +  524288, 131072, 131072);
  cvt(w3W,  w123B + 1048576, 131072, 131072);
  cvt(whW,  whB,  786432, 786432);
  cvt(wd1W, wd1B, 1048576, 1048576);
  cvt(wd2W, wd2B, 512000, 524288);
  hipLaunchKernelGGL(concat_bias3, dim3(12), dim3(256), 0, stream, w1b, w2b, w3b, bias123);

  // G1: P = relu(block-diag expert GEMM), N=3072, K=512
  hipLaunchKernelGGL((gemm256<true, true, true>), dim3(12 * 64), dim3(512), 131072, stream,
                     tubeB, 1536, w123B, 512, bias123, (void*)P, 3072, 512, 3072, 12);
  // G2: ds[:,1024:2048] = relu(P @ wh^T + b), N=1024, K=3072
  hipLaunchKernelGGL((gemm256<false, true, true>), dim3(4 * 64), dim3(512), 131072, stream,
                     P, 3072, whB, 3072, whb, (void*)(ds + 1024), 2048, 3072, 1024, 4);
  // attn: alphas -> softmax -> context into ds[:,0:1024]
  hipLaunchKernelGGL(attn_ctx, dim3(16384), dim3(256), 0, stream, P, ds);
  // G4: out1 = relu(ds @ wd1^T + b), N=2048, K=2048
  hipLaunchKernelGGL((gemm256<false, true, true>), dim3(8 * 64), dim3(512), 131072, stream,
                     ds, 2048, wd1B, 2048, wd1b, (void*)out1, 2048, 2048, 2048, 8);
  // G5: out = out1 @ wd2^T + b (fp32, N masked to 1000), K=2048
  hipLaunchKernelGGL((gemm256<false, false, false>), dim3(4 * 64), dim3(512), 131072, stream,
                     out1, 2048, wd2B, 2048, wd2b, d_out, 1000, 2048, 1000, 4);
}

// Round 6
// 420.630 us; speedup vs baseline: 1.0659x; 1.0659x over previous
//
#include <hip/hip_runtime.h>
#include <hip/hip_bf16.h>

// ClassAtt fused pipeline. GEMMs: m201-faithful 256x256 8-phase schedule.
// BK=64, 2-slot LDS double-buffer (128 KiB), 1 half-tile stage per phase,
// boundary-only counted vmcnt(4), per-phase {reads; stage; bar; lgkm0;
// sched_barrier; setprio1; 16 MFMA; setprio0; bar}. XOR swizzle (granule^row&7)
// pre-applied on global source, re-applied on ds_read (verified involution).

typedef __bf16 bf16_t;
typedef __bf16 bf16x4 __attribute__((ext_vector_type(4)));
typedef __bf16 bf16x8 __attribute__((ext_vector_type(8)));
typedef float  f32x4  __attribute__((ext_vector_type(4)));

#define AS1(p) (const __attribute__((address_space(1))) void*)(p)
#define AS3(p) (__attribute__((address_space(3))) void*)(p)

// ---------------- f32 -> bf16 conversion (vectorized, zero-pad tail) ----------------
__global__ void cvt_f32_bf16_v4(const float* __restrict__ src, bf16_t* __restrict__ dst,
                                int n4src, int n4tot) {
  for (int i = blockIdx.x * blockDim.x + threadIdx.x; i < n4tot; i += gridDim.x * blockDim.x) {
    bf16x4 o;
    if (i < n4src) {
      float4 f = ((const float4*)src)[i];
      o[0] = (bf16_t)f.x; o[1] = (bf16_t)f.y; o[2] = (bf16_t)f.z; o[3] = (bf16_t)f.w;
    } else {
      o[0] = (bf16_t)0.0f; o[1] = (bf16_t)0.0f; o[2] = (bf16_t)0.0f; o[3] = (bf16_t)0.0f;
    }
    *(bf16x4*)(dst + (size_t)i * 4) = o;
  }
}

__global__ void concat_bias3(const float* __restrict__ a, const float* __restrict__ b,
                             const float* __restrict__ c, float* __restrict__ dst) {
  int i = blockIdx.x * blockDim.x + threadIdx.x;
  if (i < 1024) dst[i] = a[i];
  else if (i < 2048) dst[i] = b[i - 1024];
  else if (i < 3072) dst[i] = c[i - 2048];
}

// ---------------- GEMM: C = act(A @ Bw^T + bias), 256x256 tile, BK=64, 8-phase ----------
// 512 threads = 8 waves (wm=w>>2 in {0,1}, wn=w&3), per-wave output 128x64.
// LDS (dynamic 128 KiB): A[slot][half] 4x16KB at 0; B[slot][half] 4x16KB at 64KB.
//   A half h = row quarters {64h..64h+64, 128+64h..128+64h+64} (i-part = quarter).
//   B half h = rows [128h, 128h+128), i-part = 64-row sub-block.
// Stage rows: 8 threads/row (16B each), swizzled source granule = (ln&7)^(ln>>3).
// Phase plan per iteration i (tiles 2i slot0 @P1-4, 2i+1 slot1 @P5-8):
//   P1:LD A(s0,h0,k0)+B(s0,k0), STAGE Ah1(s1,t1)  | MFMA h0*k0
//   P2:LD A(s0,h0,k1)+B(s0,k1), STAGE Bh1(s1,t1)  | MFMA h0*k1
//   P3:LD A(s0,h1,k0),          STAGE Ah0(s0,t2)  | MFMA h1*k0
//   P4:LD A(s0,h1,k1),          STAGE Bh0(s0,t2)  | MFMA h1*k1, vmcnt(4|0)
//   P5-P8: same on slot1, stages Ah1(s0,t2),Bh1(s0,t2),Ah0(s1,t3),Bh0(s1,t3); P8 vmcnt(4)
// WAR: every stage 1+ barrier after its region's last read (hand-verified all 8).
// RAW: boundary vmcnt(4) leaves exactly the 2 newest (future-tile) halves unconfirmed.
template<bool BDIAG, bool RELU, bool OUT_BF16>
__global__ __launch_bounds__(512, 2)
void gemm256(const bf16_t* __restrict__ A, int lda,
             const bf16_t* __restrict__ Bw, int ldb,
             const float* __restrict__ bias,
             void* __restrict__ Cout, int ldc,
             int K, int Nmask, int nbx)
{
  extern __shared__ char lds[];

  const int t   = threadIdx.x;
  const int ln  = t & 63;
  const int w   = t >> 6;
  const int l15 = ln & 15, lhi = ln >> 4;
  const int wm  = w >> 2, wn = w & 3;

  // XCD-chunked block swizzle (grid divisible by 8)
  const int nb = (int)gridDim.x;
  const int id = (int)blockIdx.x;
  const int id_sw = (id & 7) * (nb >> 3) + (id >> 3);
  const int bx = id_sw % nbx, by = id_sw / nbx;
  const int rowBase = by * 256;
  const int colBase = bx * 256;
  const int aCol0 = BDIAG ? (colBase >> 10) * 512 : 0;

  // staging source (per-lane): row = base + 8w + ln/8; col granule swizzled
  const int swcol = (((ln & 7) ^ (ln >> 3)) & 7) << 3;
  const bf16_t* srcA = A  + (size_t)(rowBase + 8 * w + (ln >> 3)) * lda + aCol0 + swcol;
  const bf16_t* srcB = Bw + (size_t)(colBase + 8 * w + (ln >> 3)) * ldb + swcol;
  char* ldsA_w = lds + w * 1024;
  char* ldsB_w = lds + 65536 + w * 1024;

  // fragment read byte offsets (within A-region / B-region), swizzled:
  //   A: + slot*32768 + h*16384 ; sub-frag offsets {0,2048,4096,6144}
  const int aRd0 = wm * 8192 + l15 * 128 + (((0 * 4 + lhi) ^ (l15 & 7)) << 4);
  const int aRd1 = wm * 8192 + l15 * 128 + (((1 * 4 + lhi) ^ (l15 & 7)) << 4);
  const int bRd0 = (wn >> 1) * 16384 + (wn & 1) * 8192 + l15 * 128 + (((0 * 4 + lhi) ^ (l15 & 7)) << 4);
  const int bRd1 = (wn >> 1) * 16384 + (wn & 1) * 8192 + l15 * 128 + (((1 * 4 + lhi) ^ (l15 & 7)) << 4);

  const int nt = K >> 6;        // BK=64 tiles (K in {512,2048,3072} -> 8/32/48)
  const int ni = nt >> 1;       // iterations (pairs of tiles)

  f32x4 acc[8][4] = {};
  bf16x8 aR[4], bR0[4], bR1[4];

  #define STAGE_A(s, h, tile)                                                          \
    do {                                                                               \
      const bf16_t* p_ = srcA + (size_t)(64 * (h)) * lda + (size_t)(tile) * 64;        \
      char* d_ = ldsA_w + (s) * 32768 + (h) * 16384;                                   \
      __builtin_amdgcn_global_load_lds(AS1(p_), AS3(d_), 16, 0, 0);                    \
      __builtin_amdgcn_global_load_lds(AS1(p_ + (size_t)128 * lda), AS3(d_ + 8192), 16, 0, 0); \
    } while (0)

  #define STAGE_B(s, h, tile)                                                          \
    do {                                                                               \
      const bf16_t* p_ = srcB + (size_t)(128 * (h)) * ldb + (size_t)(tile) * 64;       \
      char* d_ = ldsB_w + (s) * 32768 + (h) * 16384;                                   \
      __builtin_amdgcn_global_load_lds(AS1(p_), AS3(d_), 16, 0, 0);                    \
      __builtin_amdgcn_global_load_lds(AS1(p_ + (size_t)64 * ldb), AS3(d_ + 8192), 16, 0, 0); \
    } while (0)

  #define LD_A(s, h, AOFF)                                                             \
    do {                                                                               \
      const char* p_ = lds + (s) * 32768 + (h) * 16384 + (AOFF);                       \
      aR[0] = *(const bf16x8*)(p_);        aR[1] = *(const bf16x8*)(p_ + 2048);        \
      aR[2] = *(const bf16x8*)(p_ + 4096); aR[3] = *(const bf16x8*)(p_ + 6144);        \
    } while (0)

  #define LD_B(s, BOFF, BR)                                                            \
    do {                                                                               \
      const char* p_ = lds + 65536 + (s) * 32768 + (BOFF);                             \
      BR[0] = *(const bf16x8*)(p_);        BR[1] = *(const bf16x8*)(p_ + 2048);        \
      BR[2] = *(const bf16x8*)(p_ + 4096); BR[3] = *(const bf16x8*)(p_ + 6144);        \
    } while (0)

  #define MM(H, BR)                                                                    \
    do {                                                                               \
      __builtin_amdgcn_s_setprio(1);                                                   \
      _Pragma("unroll")                                                                \
      for (int m_ = 0; m_ < 4; ++m_)                                                   \
        _Pragma("unroll")                                                              \
        for (int n_ = 0; n_ < 4; ++n_)                                                 \
          acc[(H) * 4 + m_][n_] = __builtin_amdgcn_mfma_f32_16x16x32_bf16(             \
              aR[m_], BR[n_], acc[(H) * 4 + m_][n_], 0, 0, 0);                         \
      __builtin_amdgcn_s_setprio(0);                                                   \
    } while (0)

  #define BAR_MID()                                                                    \
    do {                                                                               \
      __builtin_amdgcn_s_barrier();                                                    \
      asm volatile("s_waitcnt lgkmcnt(0)" ::: "memory");                               \
      __builtin_amdgcn_sched_barrier(0);                                               \
    } while (0)

  #define BAR_END()                                                                    \
    do { __builtin_amdgcn_s_barrier(); asm volatile("" ::: "memory"); } while (0)

  // ---- prologue: tile0 complete + tile1 Ah0,Bh0 (12 loads); confirm tile0 ----
  STAGE_A(0, 0, 0); STAGE_B(0, 0, 0); STAGE_A(0, 1, 0); STAGE_B(0, 1, 0);
  STAGE_A(1, 0, 1); STAGE_B(1, 0, 1);
  asm volatile("s_waitcnt vmcnt(4)" ::: "memory");
  __builtin_amdgcn_s_barrier();
  asm volatile("" ::: "memory");

  for (int i = 0; i < ni; ++i) {
    const bool nl = (i + 1 < ni);
    const int t1 = 2 * i + 1, t2 = 2 * i + 2, t3 = 2 * i + 3;

    // P1
    LD_A(0, 0, aRd0); LD_B(0, bRd0, bR0);
    STAGE_A(1, 1, t1);
    BAR_MID(); MM(0, bR0); BAR_END();
    // P2
    LD_A(0, 0, aRd1); LD_B(0, bRd1, bR1);
    STAGE_B(1, 1, t1);
    BAR_MID(); MM(0, bR1); BAR_END();
    // P3
    LD_A(0, 1, aRd0);
    if (nl) STAGE_A(0, 0, t2);
    BAR_MID(); MM(1, bR0); BAR_END();
    // P4 (tile boundary)
    LD_A(0, 1, aRd1);
    if (nl) STAGE_B(0, 0, t2);
    BAR_MID(); MM(1, bR1);
    if (nl) { asm volatile("s_waitcnt vmcnt(4)" ::: "memory"); }
    else    { asm volatile("s_waitcnt vmcnt(0)" ::: "memory"); }
    BAR_END();
    // P5
    LD_A(1, 0, aRd0); LD_B(1, bRd0, bR0);
    if (nl) STAGE_A(0, 1, t2);
    BAR_MID(); MM(0, bR0); BAR_END();
    // P6
    LD_A(1, 0, aRd1); LD_B(1, bRd1, bR1);
    if (nl) STAGE_B(0, 1, t2);
    BAR_MID(); MM(0, bR1); BAR_END();
    // P7
    LD_A(1, 1, aRd0);
    if (nl) STAGE_A(1, 0, t3);
    BAR_MID(); MM(1, bR0); BAR_END();
    // P8 (tile boundary)
    LD_A(1, 1, aRd1);
    if (nl) STAGE_B(1, 0, t3);
    BAR_MID(); MM(1, bR1);
    if (nl) { asm volatile("s_waitcnt vmcnt(4)" ::: "memory"); }
    BAR_END();
  }
  #undef STAGE_A
  #undef STAGE_B
  #undef LD_A
  #undef LD_B
  #undef MM
  #undef BAR_MID
  #undef BAR_END

  // epilogue: C/D layout col=l15, row=lhi*4+i (verified)
  #pragma unroll
  for (int mf = 0; mf < 8; ++mf) {
    const int row = rowBase + wm * 128 + mf * 16 + lhi * 4;
    #pragma unroll
    for (int nf = 0; nf < 4; ++nf) {
      const int col = colBase + wn * 64 + nf * 16 + l15;
      const float bv = (col < Nmask) ? bias[col] : 0.0f;
      #pragma unroll
      for (int i = 0; i < 4; ++i) {
        float v = acc[mf][nf][i] + bv;
        if (RELU) v = fmaxf(v, 0.0f);
        if (OUT_BF16) {
          ((bf16_t*)Cout)[(size_t)(row + i) * ldc + col] = (bf16_t)v;
        } else {
          if (col < Nmask) ((float*)Cout)[(size_t)(row + i) * ldc + col] = v;
        }
      }
    }
  }
}

// ---------------- alphas -> softmax -> context (one block per row) ----------------
__global__ __launch_bounds__(256)
void attn_ctx(const bf16_t* __restrict__ P, bf16_t* __restrict__ ds) {
  __shared__ float red[3][4];
  __shared__ float wsh[3];
  const int r = blockIdx.x;
  const int t = threadIdx.x;
  const bf16_t* Prow = P + (size_t)r * 3072;
  bf16_t* dsrow = ds + (size_t)r * 2048;

  const int j = t * 4;
  bf16x4 lv = *(const bf16x4*)(dsrow + 1024 + j);
  float lhv[4], pv[3][4];
  float s[3] = {0.f, 0.f, 0.f};
  #pragma unroll
  for (int q = 0; q < 4; q++) lhv[q] = (float)lv[q];
  #pragma unroll
  for (int e = 0; e < 3; e++) {
    bf16x4 p = *(const bf16x4*)(Prow + e * 1024 + j);
    #pragma unroll
    for (int q = 0; q < 4; q++) {
      pv[e][q] = (float)p[q];
      s[e] += lhv[q] * pv[e][q];
    }
  }
  #pragma unroll
  for (int off = 32; off > 0; off >>= 1) {
    #pragma unroll
    for (int e = 0; e < 3; e++) s[e] += __shfl_down(s[e], off, 64);
  }
  const int w = t >> 6, l = t & 63;
  if (l == 0) {
    #pragma unroll
    for (int e = 0; e < 3; e++) red[e][w] = s[e];
  }
  __syncthreads();
  if (t == 0) {
    float a0 = red[0][0] + red[0][1] + red[0][2] + red[0][3];
    float a1 = red[1][0] + red[1][1] + red[1][2] + red[1][3];
    float a2 = red[2][0] + red[2][1] + red[2][2] + red[2][3];
    float mx = fmaxf(a0, fmaxf(a1, a2));
    float e0 = expf(a0 - mx), e1 = expf(a1 - mx), e2 = expf(a2 - mx);
    float inv = 1.0f / (e0 + e1 + e2);
    wsh[0] = e0 * inv; wsh[1] = e1 * inv; wsh[2] = e2 * inv;
  }
  __syncthreads();
  const float w0 = wsh[0], w1 = wsh[1], w2 = wsh[2];
  bf16x4 o;
  #pragma unroll
  for (int q = 0; q < 4; q++)
    o[q] = (bf16_t)(w0 * pv[0][q] + w1 * pv[1][q] + w2 * pv[2][q]);
  *(bf16x4*)(dsrow + j) = o;
}

// ---------------- launch ----------------
extern "C" void kernel_launch(void* const* d_in, const int* in_sizes, int n_in,
                              void* d_out, int out_size, void* d_ws, size_t ws_size,
                              hipStream_t stream) {
  (void)in_sizes; (void)n_in; (void)out_size; (void)ws_size;

  const float* tube = (const float*)d_in[0];
  const float* w1W  = (const float*)d_in[1];
  const float* w1b  = (const float*)d_in[2];
  const float* w2W  = (const float*)d_in[3];
  const float* w2b  = (const float*)d_in[4];
  const float* w3W  = (const float*)d_in[5];
  const float* w3b  = (const float*)d_in[6];
  const float* whW  = (const float*)d_in[7];
  const float* whb  = (const float*)d_in[8];
  const float* wd1W = (const float*)d_in[9];
  const float* wd1b = (const float*)d_in[10];
  const float* wd2W = (const float*)d_in[11];
  const float* wd2b = (const float*)d_in[12];

  // workspace layout (bytes); out1 aliases {whB, w123B, tubeB} which are dead by G4.
  char* ws = (char*)d_ws;
  bf16_t* P       = (bf16_t*)(ws + 0);            // 16384x3072
  bf16_t* ds      = (bf16_t*)(ws + 100663296);    // 16384x2048
  bf16_t* wd1B    = (bf16_t*)(ws + 167772160);    // 2048x2048
  bf16_t* wd2B    = (bf16_t*)(ws + 176160768);    // 1024x2048 (rows 1000.. zero)
  bf16_t* whB     = (bf16_t*)(ws + 180355072);    // 1024x3072
  bf16_t* w123B   = (bf16_t*)(ws + 186646528);    // 3072x512
  bf16_t* tubeB   = (bf16_t*)(ws + 189792256);    // 16384x1536
  bf16_t* out1    = (bf16_t*)(ws + 180355072);    // 16384x2048, aliases whB..tubeB
  float*  bias123 = (float*)(ws + 247463936);     // 3072 f32

  // allow 128 KiB dynamic LDS for the gemm instantiations
  hipFuncSetAttribute((const void*)(gemm256<true,  true,  true >),
                      hipFuncAttributeMaxDynamicSharedMemorySize, 131072);
  hipFuncSetAttribute((const void*)(gemm256<false, true,  true >),
                      hipFuncAttributeMaxDynamicSharedMemorySize, 131072);
  hipFuncSetAttribute((const void*)(gemm256<false, false, false>),
                      hipFuncAttributeMaxDynamicSharedMemorySize, 131072);

  auto cvt = [&](const float* s, bf16_t* d, int n4s, int n4t) {
    int nb = (n4t + 255) / 256; if (nb > 2048) nb = 2048;
    hipLaunchKernelGGL(cvt_f32_bf16_v4, dim3(nb), dim3(256), 0, stream, s, d, n4s, n4t);
  };
  cvt(tube, tubeB, 6291456, 6291456);
  cvt(w1W,  w123B,           131072, 131072);
  cvt(w2W,  w123B +  524288, 131072, 131072);
  cvt(w3W,  w123B + 1048576, 131072, 131072);
  cvt(whW,  whB,  786432, 786432);
  cvt(wd1W, wd1B, 1048576, 1048576);
  cvt(wd2W, wd2B, 512000, 524288);
  hipLaunchKernelGGL(concat_bias3, dim3(12), dim3(256), 0, stream, w1b, w2b, w3b, bias123);

  // G1: P = relu(block-diag expert GEMM), N=3072, K=512
  hipLaunchKernelGGL((gemm256<true, true, true>), dim3(12 * 64), dim3(512), 131072, stream,
                     tubeB, 1536, w123B, 512, bias123, (void*)P, 3072, 512, 3072, 12);
  // G2: ds[:,1024:2048] = relu(P @ wh^T + b), N=1024, K=3072
  hipLaunchKernelGGL((gemm256<false, true, true>), dim3(4 * 64), dim3(512), 131072, stream,
                     P, 3072, whB, 3072, whb, (void*)(ds + 1024), 2048, 3072, 1024, 4);
  // attn: alphas -> softmax -> context into ds[:,0:1024]
  hipLaunchKernelGGL(attn_ctx, dim3(16384), dim3(256), 0, stream, P, ds);
  // G4: out1 = relu(ds @ wd1^T + b), N=2048, K=2048
  hipLaunchKernelGGL((gemm256<false, true, true>), dim3(8 * 64), dim3(512), 131072, stream,
                     ds, 2048, wd1B, 2048, wd1b, (void*)out1, 2048, 2048, 2048, 8);
  // G5: out = out1 @ wd2^T + b (fp32, N masked to 1000), K=2048
  hipLaunchKernelGGL((gemm256<false, false, false>), dim3(4 * 64), dim3(512), 131072, stream,
                     out1, 2048, wd2B, 2048, wd2b, d_out, 1000, 2048, 1000, 4);
}